// Round 1
// baseline (1046.500 us; speedup 1.0000x reference)
//
#include <hip/hip_runtime.h>

// Non-local (SAGAN) block: B=8, C=256, C'=64, N=64*64=4096.
// y = gamma * (Wo @ (const2 * softmax((Wq xs)^T (Wk xs)) applied to (Wv xs)) + bo) + x
// xs = const1 * x.  Flash-style: never materialize the [B,4096,4096] scores.
//
// Round 1 baseline: fp32 vector-ALU, 3 kernels via 32 MiB workspace:
//   [q | k | v | sa_t]  (sa stored transposed [b][n][cp] so flash writes coalesce)

#define Bsz 8
#define Cch 256
#define CPd 64
#define Nn  4096
#define TIL 64
#define PAD 68   // LDS row stride in floats: ==4 mod 16 floats -> conflict-free b128 per-lane rows

static constexpr float C1 = (float)(1.41421 / 16.0);  // ROOT_2 / sqrt(256)
static constexpr float C2 = (float)(1.41421 / 8.0);   // ROOT_2 / sqrt(64)

// ---------------------------------------------------------------- QKV proj --
__global__ __launch_bounds__(256) void qkv_proj_kernel(
    const float* __restrict__ x,
    const float* __restrict__ Wq, const float* __restrict__ bq,
    const float* __restrict__ Wk, const float* __restrict__ bk,
    const float* __restrict__ Wv, const float* __restrict__ bv,
    float* __restrict__ qo, float* __restrict__ ko, float* __restrict__ vo)
{
    __shared__ __align__(16) float xs[Cch * TIL];   // [c][n], stride 64
    __shared__ __align__(16) float Ws[CPd * TIL];   // [o][ci] chunk, stride 64
    const int b  = blockIdx.y;
    const int n0 = blockIdx.x * TIL;
    const int t  = threadIdx.x;
    const int ml = t & 63;      // lane -> n within tile
    const int g  = t >> 6;      // wave -> o-quarter

    const float* xb = x + (size_t)b * Cch * Nn;
    for (int i = t; i < Cch * TIL; i += 256) {
        int c = i >> 6, n = i & 63;
        xs[i] = C1 * xb[c * Nn + n0 + n];
    }

    const float* Wm[3] = {Wq, Wk, Wv};
    const float* bm[3] = {bq, bk, bv};
    float*       om[3] = {qo, ko, vo};

    for (int mat = 0; mat < 3; ++mat) {
        const float* W = Wm[mat];
        float acc[16];
        #pragma unroll
        for (int oi = 0; oi < 16; ++oi) acc[oi] = bm[mat][g * 16 + oi];

        for (int cc = 0; cc < Cch; cc += TIL) {
            __syncthreads();  // xs ready (first iter) / Ws no longer read (later)
            for (int i = t; i < CPd * TIL; i += 256) {
                int o = i >> 6, ci = i & 63;
                Ws[i] = W[o * Cch + cc + ci];
            }
            __syncthreads();
            #pragma unroll 4
            for (int c4 = 0; c4 < 16; ++c4) {
                float x0 = xs[(cc + c4 * 4 + 0) * TIL + ml];
                float x1 = xs[(cc + c4 * 4 + 1) * TIL + ml];
                float x2 = xs[(cc + c4 * 4 + 2) * TIL + ml];
                float x3 = xs[(cc + c4 * 4 + 3) * TIL + ml];
                #pragma unroll
                for (int oi = 0; oi < 16; ++oi) {
                    const float4 w = *(const float4*)&Ws[(g * 16 + oi) * TIL + c4 * 4];
                    acc[oi] = fmaf(w.x, x0, fmaf(w.y, x1, fmaf(w.z, x2, fmaf(w.w, x3, acc[oi]))));
                }
            }
        }
        float* op = om[mat] + (size_t)b * CPd * Nn + n0 + ml;
        #pragma unroll
        for (int oi = 0; oi < 16; ++oi)
            op[(size_t)(g * 16 + oi) * Nn] = acc[oi];
    }
}

// ------------------------------------------------------------ flash attention
// Block = (batch b, 64 query rows n0..n0+63). Online softmax over 64 KV tiles.
// S-phase: thread (g,ml): row n=ml, cols m=g*16..+16 (per-lane Q b32, K bcast b128)
// PV-phase: thread (g,ml): O[c=ml][n=g*16+ni]     (per-lane V b128, P bcast b128)
__global__ __launch_bounds__(256) void flash_kernel(
    const float* __restrict__ qi, const float* __restrict__ ki,
    const float* __restrict__ vi, float* __restrict__ sa_t /* [b][n][cp] */)
{
    __shared__ __align__(16) float Qs[CPd * TIL];   // [c][n], stride 64
    __shared__ __align__(16) float Ks[CPd * PAD];   // [c][m]
    __shared__ __align__(16) float Vs[CPd * PAD];   // [c][m]
    __shared__ __align__(16) float Ps[TIL * PAD];   // [n][m]
    __shared__ float redmax[4 * TIL];
    __shared__ float redsum[4 * TIL];
    __shared__ float alphas[TIL];
    __shared__ float Ls[TIL];

    const int b  = blockIdx.y;
    const int n0 = blockIdx.x * TIL;
    const int t  = threadIdx.x;
    const int ml = t & 63;
    const int g  = t >> 6;

    const float* qb = qi + (size_t)b * CPd * Nn;
    const float* kb = ki + (size_t)b * CPd * Nn;
    const float* vb = vi + (size_t)b * CPd * Nn;

    for (int i = t; i < CPd * TIL; i += 256) {
        int c = i >> 6, n = i & 63;
        Qs[i] = qb[c * Nn + n0 + n];
    }

    float acc[16];
    #pragma unroll
    for (int ni = 0; ni < 16; ++ni) acc[ni] = 0.f;
    float Mrow = -__builtin_inff();
    float Lrow = 0.f;

    for (int m0 = 0; m0 < Nn; m0 += TIL) {
        __syncthreads();  // prev tile's PV reads done; Q load done (first iter)
        for (int i4 = t; i4 < CPd * 16; i4 += 256) {   // K,V tiles, float4
            int c = i4 >> 4, j = i4 & 15;
            *(float4*)&Ks[c * PAD + 4 * j] = *(const float4*)(kb + (size_t)c * Nn + m0 + 4 * j);
            *(float4*)&Vs[c * PAD + 4 * j] = *(const float4*)(vb + (size_t)c * Nn + m0 + 4 * j);
        }
        __syncthreads();

        // ---- S = Q^T K (row n=ml, 16 cols) ----
        float s[16];
        #pragma unroll
        for (int mi = 0; mi < 16; ++mi) s[mi] = 0.f;
        #pragma unroll 4
        for (int ci = 0; ci < CPd; ++ci) {
            float qv = Qs[ci * TIL + ml];
            float kk[16];
            const float4* kr4 = (const float4*)&Ks[ci * PAD + g * 16];
            *(float4*)&kk[0]  = kr4[0];
            *(float4*)&kk[4]  = kr4[1];
            *(float4*)&kk[8]  = kr4[2];
            *(float4*)&kk[12] = kr4[3];
            #pragma unroll
            for (int mi = 0; mi < 16; ++mi) s[mi] = fmaf(qv, kk[mi], s[mi]);
        }

        // ---- online softmax for row ml (state replicated across the 4 waves) ----
        float pmax = s[0];
        #pragma unroll
        for (int mi = 1; mi < 16; ++mi) pmax = fmaxf(pmax, s[mi]);
        redmax[g * TIL + ml] = pmax;
        __syncthreads();
        float tmax = fmaxf(fmaxf(redmax[ml], redmax[TIL + ml]),
                           fmaxf(redmax[2 * TIL + ml], redmax[3 * TIL + ml]));
        float Mnew  = fmaxf(Mrow, tmax);
        float alpha = __expf(Mrow - Mnew);   // first tile: exp(-inf)=0
        float p[16];
        float psum = 0.f;
        #pragma unroll
        for (int mi = 0; mi < 16; ++mi) { p[mi] = __expf(s[mi] - Mnew); psum += p[mi]; }
        *(float4*)&Ps[ml * PAD + g * 16 + 0]  = make_float4(p[0],  p[1],  p[2],  p[3]);
        *(float4*)&Ps[ml * PAD + g * 16 + 4]  = make_float4(p[4],  p[5],  p[6],  p[7]);
        *(float4*)&Ps[ml * PAD + g * 16 + 8]  = make_float4(p[8],  p[9],  p[10], p[11]);
        *(float4*)&Ps[ml * PAD + g * 16 + 12] = make_float4(p[12], p[13], p[14], p[15]);
        redsum[g * TIL + ml] = psum;
        if (g == 0) alphas[ml] = alpha;
        __syncthreads();
        float lsum = redsum[ml] + redsum[TIL + ml] + redsum[2 * TIL + ml] + redsum[3 * TIL + ml];
        Lrow = alpha * Lrow + lsum;
        Mrow = Mnew;

        // ---- O[c=ml][n=g*16+ni] = alpha*O + P V^T ----
        #pragma unroll
        for (int ni = 0; ni < 16; ++ni) acc[ni] *= alphas[g * 16 + ni];
        #pragma unroll 2
        for (int m4 = 0; m4 < 16; ++m4) {
            float4 v4 = *(const float4*)&Vs[ml * PAD + 4 * m4];
            #pragma unroll
            for (int ni = 0; ni < 16; ++ni) {
                float4 p4 = *(const float4*)&Ps[(g * 16 + ni) * PAD + 4 * m4];
                acc[ni] = fmaf(p4.x, v4.x, fmaf(p4.y, v4.y,
                          fmaf(p4.z, v4.z, fmaf(p4.w, v4.w, acc[ni]))));
            }
        }
    }

    if (g == 0) Ls[ml] = Lrow;
    __syncthreads();
    float* sab = sa_t + ((size_t)b * Nn + n0) * CPd;
    #pragma unroll
    for (int ni = 0; ni < 16; ++ni) {
        float scale = C2 / Ls[g * 16 + ni];
        sab[(g * 16 + ni) * CPd + ml] = acc[ni] * scale;   // coalesced (lane=cp)
    }
}

// ------------------------------------------------------------- output proj --
__global__ __launch_bounds__(256) void out_kernel(
    const float* __restrict__ sa_t, const float* __restrict__ Wo,
    const float* __restrict__ bo, const float* __restrict__ gamma,
    const float* __restrict__ x, float* __restrict__ y)
{
    __shared__ __align__(16) float Sas[TIL * PAD];  // [n][cp]
    __shared__ __align__(16) float Wos[TIL * PAD];  // [o'][cp] chunk
    const int b  = blockIdx.y;
    const int n0 = blockIdx.x * TIL;
    const int t  = threadIdx.x;
    const int ml = t & 63;
    const int g  = t >> 6;
    const float gam = gamma[0];

    const float* sab = sa_t + ((size_t)b * Nn + n0) * CPd;
    for (int i = t; i < TIL * CPd; i += 256) {
        int n = i >> 6, cp = i & 63;
        Sas[n * PAD + cp] = sab[n * CPd + cp];
    }
    const float* xb = x + (size_t)b * Cch * Nn;
    float*       yb = y + (size_t)b * Cch * Nn;

    for (int oc = 0; oc < Cch; oc += TIL) {
        __syncthreads();
        for (int i = t; i < TIL * CPd; i += 256) {
            int o = i >> 6, cp = i & 63;
            Wos[o * PAD + cp] = Wo[(oc + o) * CPd + cp];
        }
        __syncthreads();
        float acc[16];
        #pragma unroll
        for (int oi = 0; oi < 16; ++oi) acc[oi] = 0.f;
        #pragma unroll 4
        for (int c4 = 0; c4 < 16; ++c4) {
            float4 s4 = *(const float4*)&Sas[ml * PAD + 4 * c4];
            #pragma unroll
            for (int oi = 0; oi < 16; ++oi) {
                float4 w4 = *(const float4*)&Wos[(g * 16 + oi) * PAD + 4 * c4];
                acc[oi] = fmaf(w4.x, s4.x, fmaf(w4.y, s4.y,
                          fmaf(w4.z, s4.z, fmaf(w4.w, s4.w, acc[oi]))));
            }
        }
        #pragma unroll
        for (int oi = 0; oi < 16; ++oi) {
            int o = oc + g * 16 + oi;
            size_t idx = (size_t)o * Nn + n0 + ml;
            yb[idx] = fmaf(gam, acc[oi] + bo[o], xb[idx]);   // gamma*out + x
        }
    }
}

// ---------------------------------------------------------------------------
extern "C" void kernel_launch(void* const* d_in, const int* in_sizes, int n_in,
                              void* d_out, int out_size, void* d_ws, size_t ws_size,
                              hipStream_t stream)
{
    const float* x     = (const float*)d_in[0];
    const float* Wq    = (const float*)d_in[1];
    const float* bq    = (const float*)d_in[2];
    const float* Wk    = (const float*)d_in[3];
    const float* bk    = (const float*)d_in[4];
    const float* Wv    = (const float*)d_in[5];
    const float* bv    = (const float*)d_in[6];
    const float* Wo    = (const float*)d_in[7];
    const float* bo    = (const float*)d_in[8];
    const float* gamma = (const float*)d_in[9];
    float* y = (float*)d_out;

    const size_t per = (size_t)Bsz * CPd * Nn;   // 2,097,152 floats
    float* q  = (float*)d_ws;                    // total ws use: 32 MiB
    float* k  = q + per;
    float* v  = k + per;
    float* sa = v + per;

    dim3 grid(Nn / TIL, Bsz);
    qkv_proj_kernel<<<grid, 256, 0, stream>>>(x, Wq, bq, Wk, bk, Wv, bv, q, k, v);
    flash_kernel<<<grid, 256, 0, stream>>>(q, k, v, sa);
    out_kernel<<<grid, 256, 0, stream>>>(sa, Wo, bo, gamma, x, y);
}

// Round 2
// 324.733 us; speedup vs baseline: 3.2227x; 3.2227x over previous
//
#include <hip/hip_runtime.h>

// Non-local (SAGAN) block on MI355X. B=8, C=256, C'=64, N=4096.
// Round 2: bf16 MFMA (16x16x32) for QK^T, PV^T, and output projection.
// No online-max softmax: spectral-normed weights bound |S| <= ~2.1, exp safe.
// ws: qT[b][n][c] bf16 4MB | kT[b][n][c] bf16 4MB | vB[b][c][n] bf16 4MB | sa[b][n][cp] f32 8MB

#define Bsz 8
#define Cch 256
#define CPd 64
#define Nn  4096
#define TIL 64

typedef __attribute__((ext_vector_type(8))) short short8;   // 8 bf16 = 4 VGPRs (MFMA A/B frag)
typedef __attribute__((ext_vector_type(4))) float f32x4;    // MFMA C/D frag

static constexpr float C1 = (float)(1.41421 / 16.0);  // ROOT_2/sqrt(C)
static constexpr float C2 = (float)(1.41421 / 8.0);   // ROOT_2/sqrt(C')

__device__ inline unsigned pk_rne(float a, float b) {   // -> bf16x2 (RNE)
    unsigned ua = __float_as_uint(a); ua += 0x7FFFu + ((ua >> 16) & 1u);
    unsigned ub = __float_as_uint(b); ub += 0x7FFFu + ((ub >> 16) & 1u);
    return (ua >> 16) | (ub & 0xFFFF0000u);
}
__device__ inline unsigned short bf_rne(float a) {
    unsigned ua = __float_as_uint(a); ua += 0x7FFFu + ((ua >> 16) & 1u);
    return (unsigned short)(ua >> 16);
}
__device__ inline unsigned pk_trunc(float lo, float hi) { // -> bf16x2 (truncate), 1 v_perm
    return __builtin_amdgcn_perm(__float_as_uint(hi), __float_as_uint(lo), 0x07060302u);
}

// ---------------------------------------------------------------- QKV proj --
// fp32 VALU compute (round-1 proven); outputs bf16: qT,kT as [b][n][c], v as [b][c][n].
__global__ __launch_bounds__(256) void qkv_proj_kernel(
    const float* __restrict__ x,
    const float* __restrict__ Wq, const float* __restrict__ bq,
    const float* __restrict__ Wk, const float* __restrict__ bk,
    const float* __restrict__ Wv, const float* __restrict__ bv,
    unsigned short* __restrict__ qT, unsigned short* __restrict__ kT,
    unsigned short* __restrict__ vB)
{
    __shared__ __align__(16) float xs[Cch * TIL];
    __shared__ __align__(16) float Ws[CPd * TIL];
    const int b  = blockIdx.y;
    const int n0 = blockIdx.x * TIL;
    const int t  = threadIdx.x;
    const int ml = t & 63;
    const int g  = t >> 6;

    const float* xb = x + (size_t)b * Cch * Nn;
    for (int i = t; i < Cch * TIL; i += 256) {
        int c = i >> 6, n = i & 63;
        xs[i] = C1 * xb[c * Nn + n0 + n];
    }

    const float* Wm[3] = {Wq, Wk, Wv};
    const float* bm[3] = {bq, bk, bv};

    for (int mat = 0; mat < 3; ++mat) {
        const float* W = Wm[mat];
        float acc[16];
        #pragma unroll
        for (int oi = 0; oi < 16; ++oi) acc[oi] = bm[mat][g * 16 + oi];

        for (int cc = 0; cc < Cch; cc += TIL) {
            __syncthreads();
            for (int i = t; i < CPd * TIL; i += 256) {
                int o = i >> 6, ci = i & 63;
                Ws[i] = W[o * Cch + cc + ci];
            }
            __syncthreads();
            #pragma unroll 4
            for (int c4 = 0; c4 < 16; ++c4) {
                float x0 = xs[(cc + c4 * 4 + 0) * TIL + ml];
                float x1 = xs[(cc + c4 * 4 + 1) * TIL + ml];
                float x2 = xs[(cc + c4 * 4 + 2) * TIL + ml];
                float x3 = xs[(cc + c4 * 4 + 3) * TIL + ml];
                #pragma unroll
                for (int oi = 0; oi < 16; ++oi) {
                    const float4 w = *(const float4*)&Ws[(g * 16 + oi) * TIL + c4 * 4];
                    acc[oi] = fmaf(w.x, x0, fmaf(w.y, x1, fmaf(w.z, x2, fmaf(w.w, x3, acc[oi]))));
                }
            }
        }
        if (mat == 2) {   // v: [b][c][n] bf16
            unsigned short* vp = vB + (size_t)(b * CPd + g * 16) * Nn + n0 + ml;
            #pragma unroll
            for (int oi = 0; oi < 16; ++oi) vp[(size_t)oi * Nn] = bf_rne(acc[oi]);
        } else {          // q/k: [b][n][c] bf16, lane writes 32B contiguous
            unsigned short* qp = (mat == 0 ? qT : kT) + (size_t)(b * Nn + n0 + ml) * CPd + g * 16;
            unsigned d0 = pk_rne(acc[0], acc[1]),  d1 = pk_rne(acc[2], acc[3]);
            unsigned d2 = pk_rne(acc[4], acc[5]),  d3 = pk_rne(acc[6], acc[7]);
            unsigned d4 = pk_rne(acc[8], acc[9]),  d5 = pk_rne(acc[10], acc[11]);
            unsigned d6 = pk_rne(acc[12], acc[13]), d7 = pk_rne(acc[14], acc[15]);
            *(uint4*)qp       = make_uint4(d0, d1, d2, d3);
            *(uint4*)(qp + 8) = make_uint4(d4, d5, d6, d7);
        }
    }
}

// ------------------------------------------------------------ flash (MFMA) --
// Block = (b, 64 query rows). Wave g owns n-strip [16g,16g+16).
// S-phase:  S[64x64] via mfma(Q-frag, K-frag); P=exp(S) -> LDS f32 (C/D layout write).
// PV-phase: O[64x64] via mfma(P-frag from LDS, V-frag); no rescaling (no online max).
__global__ __launch_bounds__(256) void flash_kernel(
    const unsigned short* __restrict__ qT, const unsigned short* __restrict__ kT,
    const unsigned short* __restrict__ vB, float* __restrict__ sa_t)
{
    __shared__ __align__(16) unsigned short Qs[TIL * 72];  // [n][c], stride 72 (+8 pad)
    __shared__ __align__(16) unsigned short Ks[TIL * 72];  // [m][c]
    __shared__ __align__(16) unsigned short Vs[TIL * 72];  // [c][m]
    __shared__ __align__(16) float Ps[TIL * 68];           // [n][m] f32, stride 68
    __shared__ float Lsh[TIL];

    const int b   = blockIdx.y;
    const int n0  = blockIdx.x * TIL;
    const int t   = threadIdx.x;
    const int l   = t & 63;
    const int g   = t >> 6;
    const int l15 = l & 15;
    const int l4  = l >> 4;

    // stage Q tile (global [b][n][c] bf16: 64 rows x 128B, contiguous 8KB)
    {
        const uint4* qg = (const uint4*)(qT + (size_t)(b * Nn + n0) * CPd);
        int r = t >> 3, cc = t & 7;
        uint4 v0 = qg[r * 8 + cc];
        uint4 v1 = qg[(r + 32) * 8 + cc];
        *(uint4*)&Qs[r * 72 + 8 * cc]        = v0;
        *(uint4*)&Qs[(r + 32) * 72 + 8 * cc] = v1;
    }
    if (t < TIL) Lsh[t] = 0.f;
    __syncthreads();

    // hoist Q A-frags: A[n=16g+l15][c=8*l4+j (+32*ks)]
    const short8 qf0 = *(const short8*)&Qs[(16 * g + l15) * 72 + 8 * l4];
    const short8 qf1 = *(const short8*)&Qs[(16 * g + l15) * 72 + 8 * l4 + 32];

    f32x4 acco[4];
    #pragma unroll
    for (int ct = 0; ct < 4; ++ct) acco[ct] = (f32x4){0.f, 0.f, 0.f, 0.f};
    float Lp[4] = {0.f, 0.f, 0.f, 0.f};

    const uint4* kg = (const uint4*)(kT + (size_t)b * Nn * CPd);
    const unsigned short* vb = vB + (size_t)b * CPd * Nn;

    for (int m0 = 0; m0 < Nn; m0 += TIL) {
        __syncthreads();   // prior S/PV reads of Ks/Vs/Ps done
        {   // stage K [m][c] and V [c][m]
            int r = t >> 3, cc = t & 7;
            uint4 k0 = kg[(m0 + r) * 8 + cc];
            uint4 k1 = kg[(m0 + r + 32) * 8 + cc];
            *(uint4*)&Ks[r * 72 + 8 * cc]        = k0;
            *(uint4*)&Ks[(r + 32) * 72 + 8 * cc] = k1;
            uint4 w0 = *(const uint4*)(vb + (size_t)r * Nn + m0 + 8 * cc);
            uint4 w1 = *(const uint4*)(vb + (size_t)(r + 32) * Nn + m0 + 8 * cc);
            *(uint4*)&Vs[r * 72 + 8 * cc]        = w0;
            *(uint4*)&Vs[(r + 32) * 72 + 8 * cc] = w1;
        }
        __syncthreads();

        // ---- S = Q^T K: 4 col-subtiles x 2 k-steps ----
        f32x4 accs[4];
        #pragma unroll
        for (int st = 0; st < 4; ++st) {
            accs[st] = (f32x4){0.f, 0.f, 0.f, 0.f};
            const short8 kf0 = *(const short8*)&Ks[(16 * st + l15) * 72 + 8 * l4];
            const short8 kf1 = *(const short8*)&Ks[(16 * st + l15) * 72 + 8 * l4 + 32];
            accs[st] = __builtin_amdgcn_mfma_f32_16x16x32_bf16(qf0, kf0, accs[st], 0, 0, 0);
            accs[st] = __builtin_amdgcn_mfma_f32_16x16x32_bf16(qf1, kf1, accs[st], 0, 0, 0);
        }

        // ---- P = exp(S); row-sum partials; write P to LDS (C/D layout: row=4*l4+r, col=l15) ----
        #pragma unroll
        for (int st = 0; st < 4; ++st) {
            #pragma unroll
            for (int r = 0; r < 4; ++r) {
                float p = __expf(accs[st][r]);
                Lp[r] += p;
                Ps[(16 * g + 4 * l4 + r) * 68 + 16 * st + l15] = p;
            }
        }
        __syncthreads();   // P visible to all waves

        // ---- O += P V^T: A-frag P[n=16g+l15][m=8*l4+j+32ks], B-frag V[c=16ct+l15][m] ----
        #pragma unroll
        for (int ks = 0; ks < 2; ++ks) {
            const float4 a0 = *(const float4*)&Ps[(16 * g + l15) * 68 + 8 * l4 + 32 * ks];
            const float4 a1 = *(const float4*)&Ps[(16 * g + l15) * 68 + 8 * l4 + 32 * ks + 4];
            union { unsigned u[4]; short8 s; } pu;
            pu.u[0] = pk_trunc(a0.x, a0.y); pu.u[1] = pk_trunc(a0.z, a0.w);
            pu.u[2] = pk_trunc(a1.x, a1.y); pu.u[3] = pk_trunc(a1.z, a1.w);
            #pragma unroll
            for (int ct = 0; ct < 4; ++ct) {
                const short8 vf = *(const short8*)&Vs[(16 * ct + l15) * 72 + 8 * l4 + 32 * ks];
                acco[ct] = __builtin_amdgcn_mfma_f32_16x16x32_bf16(pu.s, vf, acco[ct], 0, 0, 0);
            }
        }
    }

    // L row-sums: lane's Lp[r] belongs to row 16g + 4*l4 + r (16 lanes contribute per row)
    #pragma unroll
    for (int r = 0; r < 4; ++r) atomicAdd(&Lsh[16 * g + 4 * l4 + r], Lp[r]);
    __syncthreads();

    float* sab = sa_t + (size_t)(b * Nn + n0) * CPd;
    #pragma unroll
    for (int r = 0; r < 4; ++r) {
        const float sc = C2 / Lsh[16 * g + 4 * l4 + r];
        #pragma unroll
        for (int ct = 0; ct < 4; ++ct)
            sab[(size_t)(16 * g + 4 * l4 + r) * CPd + 16 * ct + l15] = acco[ct][r] * sc;
    }
}

// ------------------------------------------------------- output proj (MFMA) --
// out[o][n] = sum_cp Wo[o][cp] * sa_t[n][cp];  y = gamma*(out+bo) + x
__global__ __launch_bounds__(256) void out_kernel(
    const float* __restrict__ sa_t, const float* __restrict__ Wo,
    const float* __restrict__ bo, const float* __restrict__ gamma,
    const float* __restrict__ x, float* __restrict__ y)
{
    __shared__ __align__(16) unsigned short Wos[Cch * 72];  // [o][cp] bf16, 36 KB
    __shared__ __align__(16) unsigned short Sas[TIL * 72];  // [n][cp] bf16
    __shared__ float bos[Cch];

    const int b   = blockIdx.y;
    const int n0  = blockIdx.x * TIL;
    const int t   = threadIdx.x;
    const int l   = t & 63;
    const int g   = t >> 6;
    const int l15 = l & 15;
    const int l4  = l >> 4;

    bos[t] = bo[t];
    {
        const int seg = t & 3;          // 16 cp per segment
        #pragma unroll
        for (int p = 0; p < 4; ++p) {   // Wo: 256 rows, 4 threads/row
            const int row = p * 64 + (t >> 2);
            const float4* wr = (const float4*)(Wo + (size_t)row * CPd + seg * 16);
            float4 w0 = wr[0], w1 = wr[1], w2 = wr[2], w3 = wr[3];
            *(uint4*)&Wos[row * 72 + seg * 16] =
                make_uint4(pk_rne(w0.x, w0.y), pk_rne(w0.z, w0.w),
                           pk_rne(w1.x, w1.y), pk_rne(w1.z, w1.w));
            *(uint4*)&Wos[row * 72 + seg * 16 + 8] =
                make_uint4(pk_rne(w2.x, w2.y), pk_rne(w2.z, w2.w),
                           pk_rne(w3.x, w3.y), pk_rne(w3.z, w3.w));
        }
        const float* sab = sa_t + (size_t)(b * Nn + n0) * CPd;
        const int n = t >> 2;
        const float4* sr = (const float4*)(sab + (size_t)n * CPd + seg * 16);
        float4 s0 = sr[0], s1 = sr[1], s2 = sr[2], s3 = sr[3];
        *(uint4*)&Sas[n * 72 + seg * 16] =
            make_uint4(pk_rne(s0.x, s0.y), pk_rne(s0.z, s0.w),
                       pk_rne(s1.x, s1.y), pk_rne(s1.z, s1.w));
        *(uint4*)&Sas[n * 72 + seg * 16 + 8] =
            make_uint4(pk_rne(s2.x, s2.y), pk_rne(s2.z, s2.w),
                       pk_rne(s3.x, s3.y), pk_rne(s3.z, s3.w));
    }
    __syncthreads();

    short8 bfr[4][2];
    #pragma unroll
    for (int ns = 0; ns < 4; ++ns) {
        bfr[ns][0] = *(const short8*)&Sas[(16 * ns + l15) * 72 + 8 * l4];
        bfr[ns][1] = *(const short8*)&Sas[(16 * ns + l15) * 72 + 8 * l4 + 32];
    }
    const float gam = gamma[0];
    const float* xb = x + (size_t)b * Cch * Nn;
    float*       yb = y + (size_t)b * Cch * Nn;

    #pragma unroll
    for (int os = 0; os < 4; ++os) {
        const int obase = 64 * g + 16 * os;
        const short8 af0 = *(const short8*)&Wos[(obase + l15) * 72 + 8 * l4];
        const short8 af1 = *(const short8*)&Wos[(obase + l15) * 72 + 8 * l4 + 32];
        #pragma unroll
        for (int ns = 0; ns < 4; ++ns) {
            f32x4 acc = (f32x4){0.f, 0.f, 0.f, 0.f};
            acc = __builtin_amdgcn_mfma_f32_16x16x32_bf16(af0, bfr[ns][0], acc, 0, 0, 0);
            acc = __builtin_amdgcn_mfma_f32_16x16x32_bf16(af1, bfr[ns][1], acc, 0, 0, 0);
            #pragma unroll
            for (int r = 0; r < 4; ++r) {
                const int o = obase + 4 * l4 + r;
                const size_t idx = (size_t)o * Nn + n0 + 16 * ns + l15;
                yb[idx] = fmaf(gam, acc[r] + bos[o], xb[idx]);
            }
        }
    }
}

// ---------------------------------------------------------------------------
extern "C" void kernel_launch(void* const* d_in, const int* in_sizes, int n_in,
                              void* d_out, int out_size, void* d_ws, size_t ws_size,
                              hipStream_t stream)
{
    (void)in_sizes; (void)n_in; (void)out_size; (void)ws_size;
    const float* x     = (const float*)d_in[0];
    const float* Wq    = (const float*)d_in[1];
    const float* bq    = (const float*)d_in[2];
    const float* Wk    = (const float*)d_in[3];
    const float* bk    = (const float*)d_in[4];
    const float* Wv    = (const float*)d_in[5];
    const float* bv    = (const float*)d_in[6];
    const float* Wo    = (const float*)d_in[7];
    const float* bo    = (const float*)d_in[8];
    const float* gamma = (const float*)d_in[9];
    float* y = (float*)d_out;

    const size_t per = (size_t)Bsz * Nn * CPd;           // 2M elements
    unsigned short* qT = (unsigned short*)d_ws;          // 4 MB
    unsigned short* kT = qT + per;                       // 4 MB
    unsigned short* vB = kT + per;                       // 4 MB
    float* sa = (float*)(vB + per);                      // 8 MB

    dim3 grid(Nn / TIL, Bsz);
    qkv_proj_kernel<<<grid, 256, 0, stream>>>(x, Wq, bq, Wk, bk, Wv, bv, qT, kT, vB);
    flash_kernel<<<grid, 256, 0, stream>>>(qT, kT, vB, sa);
    out_kernel<<<grid, 256, 0, stream>>>(sa, Wo, bo, gamma, x, y);
}

// Round 3
// 222.956 us; speedup vs baseline: 4.6937x; 1.4565x over previous
//
#include <hip/hip_runtime.h>

// Non-local (SAGAN) block on MI355X. B=8, C=256, C'=64, N=4096.
// Round 3: qkv projection rewritten as LDS-free MFMA (A-frags straight from
// global x, B-frags straight from pre-converted bf16 W); Wo pre-converted.
// ws: qT[b][n][c'] bf16 4MB | kT 4MB | vB[b][c'][n] 4MB | sa[b][n][c'] f32 8MB | Wb bf16 128KB

#define Bsz 8
#define Cch 256
#define CPd 64
#define Nn  4096
#define TIL 64

typedef __attribute__((ext_vector_type(8))) short short8;   // 8 bf16 = 4 VGPRs (MFMA A/B frag)
typedef __attribute__((ext_vector_type(4))) float f32x4;    // MFMA C/D frag

static constexpr float C1 = (float)(1.41421 / 16.0);  // ROOT_2/sqrt(C)
static constexpr float C2 = (float)(1.41421 / 8.0);   // ROOT_2/sqrt(C')

__device__ inline unsigned pk_trunc(float lo, float hi) { // -> bf16x2 (truncate), 1 v_perm
    return __builtin_amdgcn_perm(__float_as_uint(hi), __float_as_uint(lo), 0x07060302u);
}

// -------------------------------------------------------- W f32->bf16 conv --
// Wb layout: [Wq | Wk | Wv | Wo], each 16384 bf16. Runs every launch (ws re-poisoned).
__global__ __launch_bounds__(256) void wconv_kernel(
    const float* __restrict__ Wq, const float* __restrict__ Wk,
    const float* __restrict__ Wv, const float* __restrict__ Wo,
    unsigned short* __restrict__ Wb)
{
    const int idx = (blockIdx.x * 256 + threadIdx.x) * 4;   // grid 64 -> 65536 elements
    const float* src = (idx < 16384) ? Wq : (idx < 32768) ? Wk : (idx < 49152) ? Wv : Wo;
    const float4 v = *(const float4*)(src + (idx & 16383));
    *(uint2*)(Wb + idx) = make_uint2(pk_trunc(v.x, v.y), pk_trunc(v.z, v.w));
}

// --------------------------------------------------------- QKV proj (MFMA) --
// Block = (b, 64-n tile). Wave g owns n-strip [16g,16g+16).
// A-frag: xs[n][c] built from global x (8 stride-N b32 loads, scale C1, pack).
// B-frag: W[o][c] bf16 dwordx4 straight from global (L2-resident).
// D [16n x 64o] -> 17.4KB LDS tile -> packed bf16 stores (v transposed to [c'][n]).
__global__ __launch_bounds__(256) void qkv_kernel(
    const float* __restrict__ x, const unsigned short* __restrict__ Wb,
    const float* __restrict__ bq, const float* __restrict__ bk, const float* __restrict__ bv,
    unsigned short* __restrict__ qT, unsigned short* __restrict__ kT,
    unsigned short* __restrict__ vB)
{
    __shared__ __align__(16) float T[TIL * 68];

    const int b   = blockIdx.y;
    const int n0  = blockIdx.x * TIL;
    const int t   = threadIdx.x;
    const int g   = t >> 6;
    const int l15 = t & 15;
    const int l4  = (t & 63) >> 4;

    // ---- A-frags from global x: lane row n = n0 + 16g + l15, k = c = 8*l4 + j + 32*ks
    const float* xb = x + (size_t)b * Cch * Nn + n0 + 16 * g + l15;
    short8 xf[8];
    #pragma unroll
    for (int ks = 0; ks < 8; ++ks) {
        float xr[8];
        #pragma unroll
        for (int j = 0; j < 8; ++j)
            xr[j] = C1 * xb[(size_t)(8 * l4 + 32 * ks + j) * Nn];
        union { unsigned u[4]; short8 s; } p;
        p.u[0] = pk_trunc(xr[0], xr[1]); p.u[1] = pk_trunc(xr[2], xr[3]);
        p.u[2] = pk_trunc(xr[4], xr[5]); p.u[3] = pk_trunc(xr[6], xr[7]);
        xf[ks] = p.s;
    }

    #pragma unroll
    for (int mat = 0; mat < 3; ++mat) {
        const unsigned short* W = Wb + mat * 16384;          // [o=64][c=256] bf16
        const float* bias = (mat == 0) ? bq : (mat == 1) ? bk : bv;

        f32x4 acc[4];
        #pragma unroll
        for (int st = 0; st < 4; ++st) {
            const float bb = bias[16 * st + l15];            // col o = 16st+l15
            acc[st] = (f32x4){bb, bb, bb, bb};
        }
        #pragma unroll
        for (int st = 0; st < 4; ++st) {
            #pragma unroll
            for (int ks = 0; ks < 8; ++ks) {
                const short8 wf = *(const short8*)&W[(16 * st + l15) * Cch + 8 * l4 + 32 * ks];
                acc[st] = __builtin_amdgcn_mfma_f32_16x16x32_bf16(xf[ks], wf, acc[st], 0, 0, 0);
            }
        }

        __syncthreads();   // previous mat's readback done
        if (mat < 2) {     // tile as [n][c']: bank = (16*l4 + 4r + 16st + l15)%32 -> 2-way, free
            #pragma unroll
            for (int st = 0; st < 4; ++st)
                #pragma unroll
                for (int r = 0; r < 4; ++r)
                    T[(16 * g + 4 * l4 + r) * 68 + 16 * st + l15] = acc[st][r];
        } else {           // v: tile as [c'][n] (8-way on 16 writes, negligible)
            #pragma unroll
            for (int st = 0; st < 4; ++st)
                #pragma unroll
                for (int r = 0; r < 4; ++r)
                    T[(16 * st + l15) * 68 + 16 * g + 4 * l4 + r] = acc[st][r];
        }
        __syncthreads();

        const int row = t >> 2;            // n (q/k) or c' (v)
        const int sg  = 16 * (t & 3);
        const float4 a0 = *(const float4*)&T[row * 68 + sg + 0];
        const float4 a1 = *(const float4*)&T[row * 68 + sg + 4];
        const float4 a2 = *(const float4*)&T[row * 68 + sg + 8];
        const float4 a3 = *(const float4*)&T[row * 68 + sg + 12];
        const uint4 lo = make_uint4(pk_trunc(a0.x, a0.y), pk_trunc(a0.z, a0.w),
                                    pk_trunc(a1.x, a1.y), pk_trunc(a1.z, a1.w));
        const uint4 hi = make_uint4(pk_trunc(a2.x, a2.y), pk_trunc(a2.z, a2.w),
                                    pk_trunc(a3.x, a3.y), pk_trunc(a3.z, a3.w));
        unsigned short* dst;
        if (mat < 2) {     // qT/kT [b][n][c']
            dst = (mat == 0 ? qT : kT) + ((size_t)(b * Nn + n0 + row)) * CPd + sg;
        } else {           // vB [b][c'][n]
            dst = vB + ((size_t)(b * CPd + row)) * Nn + n0 + sg;
        }
        *(uint4*)dst = lo;
        *(uint4*)(dst + 8) = hi;
    }
}

// ------------------------------------------------------------ flash (MFMA) --
// (unchanged from round 2 — passed; ~LDS-pipe bound, next round's target)
__global__ __launch_bounds__(256) void flash_kernel(
    const unsigned short* __restrict__ qT, const unsigned short* __restrict__ kT,
    const unsigned short* __restrict__ vB, float* __restrict__ sa_t)
{
    __shared__ __align__(16) unsigned short Qs[TIL * 72];  // [n][c]
    __shared__ __align__(16) unsigned short Ks[TIL * 72];  // [m][c]
    __shared__ __align__(16) unsigned short Vs[TIL * 72];  // [c][m]
    __shared__ __align__(16) float Ps[TIL * 68];           // [n][m] f32
    __shared__ float Lsh[TIL];

    const int b   = blockIdx.y;
    const int n0  = blockIdx.x * TIL;
    const int t   = threadIdx.x;
    const int l   = t & 63;
    const int g   = t >> 6;
    const int l15 = l & 15;
    const int l4  = l >> 4;

    {
        const uint4* qg = (const uint4*)(qT + (size_t)(b * Nn + n0) * CPd);
        int r = t >> 3, cc = t & 7;
        uint4 v0 = qg[r * 8 + cc];
        uint4 v1 = qg[(r + 32) * 8 + cc];
        *(uint4*)&Qs[r * 72 + 8 * cc]        = v0;
        *(uint4*)&Qs[(r + 32) * 72 + 8 * cc] = v1;
    }
    if (t < TIL) Lsh[t] = 0.f;
    __syncthreads();

    const short8 qf0 = *(const short8*)&Qs[(16 * g + l15) * 72 + 8 * l4];
    const short8 qf1 = *(const short8*)&Qs[(16 * g + l15) * 72 + 8 * l4 + 32];

    f32x4 acco[4];
    #pragma unroll
    for (int ct = 0; ct < 4; ++ct) acco[ct] = (f32x4){0.f, 0.f, 0.f, 0.f};
    float Lp[4] = {0.f, 0.f, 0.f, 0.f};

    const uint4* kg = (const uint4*)(kT + (size_t)b * Nn * CPd);
    const unsigned short* vb = vB + (size_t)b * CPd * Nn;

    for (int m0 = 0; m0 < Nn; m0 += TIL) {
        __syncthreads();
        {
            int r = t >> 3, cc = t & 7;
            uint4 k0 = kg[(m0 + r) * 8 + cc];
            uint4 k1 = kg[(m0 + r + 32) * 8 + cc];
            *(uint4*)&Ks[r * 72 + 8 * cc]        = k0;
            *(uint4*)&Ks[(r + 32) * 72 + 8 * cc] = k1;
            uint4 w0 = *(const uint4*)(vb + (size_t)r * Nn + m0 + 8 * cc);
            uint4 w1 = *(const uint4*)(vb + (size_t)(r + 32) * Nn + m0 + 8 * cc);
            *(uint4*)&Vs[r * 72 + 8 * cc]        = w0;
            *(uint4*)&Vs[(r + 32) * 72 + 8 * cc] = w1;
        }
        __syncthreads();

        f32x4 accs[4];
        #pragma unroll
        for (int st = 0; st < 4; ++st) {
            accs[st] = (f32x4){0.f, 0.f, 0.f, 0.f};
            const short8 kf0 = *(const short8*)&Ks[(16 * st + l15) * 72 + 8 * l4];
            const short8 kf1 = *(const short8*)&Ks[(16 * st + l15) * 72 + 8 * l4 + 32];
            accs[st] = __builtin_amdgcn_mfma_f32_16x16x32_bf16(qf0, kf0, accs[st], 0, 0, 0);
            accs[st] = __builtin_amdgcn_mfma_f32_16x16x32_bf16(qf1, kf1, accs[st], 0, 0, 0);
        }

        #pragma unroll
        for (int st = 0; st < 4; ++st) {
            #pragma unroll
            for (int r = 0; r < 4; ++r) {
                float p = __expf(accs[st][r]);
                Lp[r] += p;
                Ps[(16 * g + 4 * l4 + r) * 68 + 16 * st + l15] = p;
            }
        }
        __syncthreads();

        #pragma unroll
        for (int ks = 0; ks < 2; ++ks) {
            const float4 a0 = *(const float4*)&Ps[(16 * g + l15) * 68 + 8 * l4 + 32 * ks];
            const float4 a1 = *(const float4*)&Ps[(16 * g + l15) * 68 + 8 * l4 + 32 * ks + 4];
            union { unsigned u[4]; short8 s; } pu;
            pu.u[0] = pk_trunc(a0.x, a0.y); pu.u[1] = pk_trunc(a0.z, a0.w);
            pu.u[2] = pk_trunc(a1.x, a1.y); pu.u[3] = pk_trunc(a1.z, a1.w);
            #pragma unroll
            for (int ct = 0; ct < 4; ++ct) {
                const short8 vf = *(const short8*)&Vs[(16 * ct + l15) * 72 + 8 * l4 + 32 * ks];
                acco[ct] = __builtin_amdgcn_mfma_f32_16x16x32_bf16(pu.s, vf, acco[ct], 0, 0, 0);
            }
        }
    }

    #pragma unroll
    for (int r = 0; r < 4; ++r) atomicAdd(&Lsh[16 * g + 4 * l4 + r], Lp[r]);
    __syncthreads();

    float* sab = sa_t + (size_t)(b * Nn + n0) * CPd;
    #pragma unroll
    for (int r = 0; r < 4; ++r) {
        const float sc = C2 / Lsh[16 * g + 4 * l4 + r];
        #pragma unroll
        for (int ct = 0; ct < 4; ++ct)
            sab[(size_t)(16 * g + 4 * l4 + r) * CPd + 16 * ct + l15] = acco[ct][r] * sc;
    }
}

// ------------------------------------------------------- output proj (MFMA) --
__global__ __launch_bounds__(256) void out_kernel(
    const float* __restrict__ sa_t, const unsigned short* __restrict__ Wob,
    const float* __restrict__ bo, const float* __restrict__ gamma,
    const float* __restrict__ x, float* __restrict__ y)
{
    __shared__ __align__(16) unsigned short Wos[Cch * 72];  // [o][cp] bf16
    __shared__ __align__(16) unsigned short Sas[TIL * 72];  // [n][cp] bf16
    __shared__ float bos[Cch];

    const int b   = blockIdx.y;
    const int n0  = blockIdx.x * TIL;
    const int t   = threadIdx.x;
    const int l   = t & 63;
    const int g   = t >> 6;
    const int l15 = l & 15;
    const int l4  = l >> 4;

    bos[t] = bo[t];
    {   // Wo bf16: 2048 uint4, coalesced copy
        const uint4* wg = (const uint4*)Wob;
        #pragma unroll
        for (int p = 0; p < 8; ++p) {
            const int idx = p * 256 + t;
            const int row = idx >> 3, seg = idx & 7;
            *(uint4*)&Wos[row * 72 + seg * 8] = wg[idx];
        }
        const float* sab = sa_t + (size_t)(b * Nn + n0) * CPd;
        const int n = t >> 2, seg = t & 3;
        const float4* sr = (const float4*)(sab + (size_t)n * CPd + seg * 16);
        float4 s0 = sr[0], s1 = sr[1], s2 = sr[2], s3 = sr[3];
        *(uint4*)&Sas[n * 72 + seg * 16] =
            make_uint4(pk_trunc(s0.x, s0.y), pk_trunc(s0.z, s0.w),
                       pk_trunc(s1.x, s1.y), pk_trunc(s1.z, s1.w));
        *(uint4*)&Sas[n * 72 + seg * 16 + 8] =
            make_uint4(pk_trunc(s2.x, s2.y), pk_trunc(s2.z, s2.w),
                       pk_trunc(s3.x, s3.y), pk_trunc(s3.z, s3.w));
    }
    __syncthreads();

    short8 bfr[4][2];
    #pragma unroll
    for (int ns = 0; ns < 4; ++ns) {
        bfr[ns][0] = *(const short8*)&Sas[(16 * ns + l15) * 72 + 8 * l4];
        bfr[ns][1] = *(const short8*)&Sas[(16 * ns + l15) * 72 + 8 * l4 + 32];
    }
    const float gam = gamma[0];
    const float* xb = x + (size_t)b * Cch * Nn;
    float*       yb = y + (size_t)b * Cch * Nn;

    #pragma unroll
    for (int os = 0; os < 4; ++os) {
        const int obase = 64 * g + 16 * os;
        const short8 af0 = *(const short8*)&Wos[(obase + l15) * 72 + 8 * l4];
        const short8 af1 = *(const short8*)&Wos[(obase + l15) * 72 + 8 * l4 + 32];
        #pragma unroll
        for (int ns = 0; ns < 4; ++ns) {
            f32x4 acc = (f32x4){0.f, 0.f, 0.f, 0.f};
            acc = __builtin_amdgcn_mfma_f32_16x16x32_bf16(af0, bfr[ns][0], acc, 0, 0, 0);
            acc = __builtin_amdgcn_mfma_f32_16x16x32_bf16(af1, bfr[ns][1], acc, 0, 0, 0);
            #pragma unroll
            for (int r = 0; r < 4; ++r) {
                const int o = obase + 4 * l4 + r;
                const size_t idx = (size_t)o * Nn + n0 + 16 * ns + l15;
                yb[idx] = fmaf(gam, acc[r] + bos[o], xb[idx]);
            }
        }
    }
}

// ---------------------------------------------------------------------------
extern "C" void kernel_launch(void* const* d_in, const int* in_sizes, int n_in,
                              void* d_out, int out_size, void* d_ws, size_t ws_size,
                              hipStream_t stream)
{
    (void)in_sizes; (void)n_in; (void)out_size; (void)ws_size;
    const float* x     = (const float*)d_in[0];
    const float* Wq    = (const float*)d_in[1];
    const float* bq    = (const float*)d_in[2];
    const float* Wk    = (const float*)d_in[3];
    const float* bk    = (const float*)d_in[4];
    const float* Wv    = (const float*)d_in[5];
    const float* bv    = (const float*)d_in[6];
    const float* Wo    = (const float*)d_in[7];
    const float* bo    = (const float*)d_in[8];
    const float* gamma = (const float*)d_in[9];
    float* y = (float*)d_out;

    const size_t per = (size_t)Bsz * Nn * CPd;           // 2M elements
    unsigned short* qT = (unsigned short*)d_ws;          // 4 MB
    unsigned short* kT = qT + per;                       // 4 MB
    unsigned short* vB = kT + per;                       // 4 MB
    float* sa = (float*)(vB + per);                      // 8 MB
    unsigned short* Wb = (unsigned short*)(sa + per);    // 128 KB: [Wq|Wk|Wv|Wo] bf16

    dim3 grid(Nn / TIL, Bsz);
    wconv_kernel<<<64, 256, 0, stream>>>(Wq, Wk, Wv, Wo, Wb);
    qkv_kernel<<<grid, 256, 0, stream>>>(x, Wb, bq, bk, bv, qT, kT, vB);
    flash_kernel<<<grid, 256, 0, stream>>>(qT, kT, vB, sa);
    out_kernel<<<grid, 256, 0, stream>>>(sa, Wb + 3 * 16384, bo, gamma, x, y);
}